// Round 5
// baseline (928.939 us; speedup 1.0000x reference)
//
#include <hip/hip_runtime.h>

// ---------------------------------------------------------------------------
// InputMapCTRNN: T=256, B=128, I=64, C=256, H=512, O=128, ALPHA=1, EPS=1e-5
//
// h[t,b,n] = relu( sum_c ctx[t,b,c]*S_c + S_bias ),
//   S_c[m,n] = sum_i x[m,i]*WbT[n, c*64+i]  -> one MFMA GEMM M=32768,N=512,
//   K=16448. Scale folded into A: ahat[m, c*64+i] = bf16(ctx[m,c]*x[m,i]),
//   built in-registers from fp32 x (v_mul + v_perm pack). B staged via
//   glds(16B) into XOR-swizzled LDS, double-buffered.
// Wave tile 32m x 64n (NOT 16x128): B-LDS traffic per wave = n*256B/kk, the
// R4 16x128 config was LDS-read-BW-bound at ~228 GB/s/CU. 64n halves it.
// Recurrence: K=320 batched MFMA  ctx' = relu([Wcc|Wic] @ [ctx;x] + bias),
//   fused in one grid with the prep blocks.
// ---------------------------------------------------------------------------

typedef unsigned int  uint_t;
typedef unsigned short ushort_t;
typedef __attribute__((ext_vector_type(8))) short  short8;
typedef __attribute__((ext_vector_type(4))) short  short4v;
typedef __attribute__((ext_vector_type(4))) float  floatx4;

__device__ __forceinline__ ushort_t f2bf(float f) {
    uint_t u = __float_as_uint(f);
    u = (u + 0x7fffu + ((u >> 16) & 1u)) >> 16;   // RNE
    return (ushort_t)u;
}
__device__ __forceinline__ uint_t pack2(float a, float b) {
    return (uint_t)f2bf(a) | ((uint_t)f2bf(b) << 16);
}
__device__ __forceinline__ float blo(uint_t u) { return __uint_as_float(u << 16); }
__device__ __forceinline__ float bhi(uint_t u) { return __uint_as_float(u & 0xffff0000u); }

__device__ __forceinline__ void glds16(const void* g, void* l) {
    __builtin_amdgcn_global_load_lds(
        (const __attribute__((address_space(1))) unsigned int*)g,
        (__attribute__((address_space(3))) unsigned int*)l, 16, 0, 0);
}

// build bf16x8 A-frag = bf16(x[0..7] * s), round-half-up, packed via v_perm
__device__ __forceinline__ short8 mkfrag(const float* xp, float s) {
    union { short8 v; uint_t u[4]; } out;
#pragma unroll
    for (int q = 0; q < 4; ++q) {
        uint_t lo = __float_as_uint(xp[2 * q] * s) + 0x8000u;
        uint_t hi = __float_as_uint(xp[2 * q + 1] * s) + 0x8000u;
        out.u[q] = __builtin_amdgcn_perm(hi, lo, 0x07060302u);  // {hi[3:2],lo[3:2]}
    }
    return out.v;
}

// ---------------------------------------------------------------------------
// FUSED: blocks 0..7 = sequential ctx recurrence; blocks 8..539 = prep
// (WbT transpose+cvt, Whh/Who -> bf16) — hides under recurrence.
// ---------------------------------------------------------------------------
__global__ __launch_bounds__(256, 1) void k_fused(
        const float* __restrict__ x, const float* __restrict__ Wcc,
        const float* __restrict__ bcc, const float* __restrict__ Wic,
        const float* __restrict__ bic, const float* __restrict__ Wmap,
        const float* __restrict__ bmap, const float* __restrict__ Whh,
        const float* __restrict__ Who,
        ushort_t* WbT, ushort_t* Whhb, ushort_t* Whob,
        float* __restrict__ CTXT, float* __restrict__ ctx_out) {
    __shared__ __align__(16) char smem[32896];   // union: prep 32896 B / rec 20480 B
    const int tid = threadIdx.x;
    const int bid = blockIdx.x;

    if (bid >= 8) {
        const int pb = bid - 8;
        if (pb < 512) {                      // WbT[n][c*64+i] = Wmap[n*64+i][c]
            float* tl = (float*)smem;        // 32*257 floats
            const int n = pb;
            for (int p = 0; p < 2; ++p) {
                if (p) __syncthreads();
#pragma unroll
                for (int k = 0; k < 32; ++k)
                    tl[k * 257 + tid] = Wmap[(size_t)(n * 64 + p * 32 + k) * 256 + tid];
                __syncthreads();
#pragma unroll
                for (int k2 = 0; k2 < 32; ++k2) {
                    int o = k2 * 256 + tid;
                    int il = o & 31, c = o >> 5;
                    WbT[(size_t)n * 16448 + c * 64 + p * 32 + il] = f2bf(tl[il * 257 + c]);
                }
            }
            if (tid < 64) WbT[(size_t)n * 16448 + 16384 + tid] = f2bf(bmap[n * 64 + tid]);
        } else if (pb < 528) {
            size_t base = (size_t)(pb - 512) * 16384;
#pragma unroll
            for (int k = 0; k < 64; ++k) { size_t i = base + k * 256 + tid; Whhb[i] = f2bf(Whh[i]); }
        } else {
            size_t base = (size_t)(pb - 528) * 16384;
#pragma unroll
            for (int k = 0; k < 64; ++k) { size_t i = base + k * 256 + tid; Whob[i] = f2bf(Who[i]); }
        }
        return;
    }

    // ---------------- recurrence: block g owns samples [g*16, g*16+16) ------
    char* bufs = smem;                          // 2 x 10240 B
    const int g = bid;
    const int lane = tid & 63, w = tid >> 6;
    const int l15 = lane & 15, quad = lane >> 4;
    const int bq = tid >> 4, o4 = tid & 15;     // x-staging role

    // A-fragments: Wcc (kb 0..7) + Wic (kb 8..9); row j = w*64+mt*16+l15
    short8 wf[4][8], wi[4][2];
#pragma unroll
    for (int mt = 0; mt < 4; ++mt) {
        const int j = w * 64 + mt * 16 + l15;
#pragma unroll
        for (int kb = 0; kb < 8; ++kb) {
            const float* src = Wcc + (size_t)j * 256 + kb * 32 + quad * 8;
            float4 a = *(const float4*)src;
            float4 b = *(const float4*)(src + 4);
            short8 s;
            s[0] = (short)f2bf(a.x); s[1] = (short)f2bf(a.y);
            s[2] = (short)f2bf(a.z); s[3] = (short)f2bf(a.w);
            s[4] = (short)f2bf(b.x); s[5] = (short)f2bf(b.y);
            s[6] = (short)f2bf(b.z); s[7] = (short)f2bf(b.w);
            wf[mt][kb] = s;
        }
#pragma unroll
        for (int kb = 0; kb < 2; ++kb) {
            const float* src = Wic + (size_t)j * 64 + kb * 32 + quad * 8;
            float4 a = *(const float4*)src;
            float4 b = *(const float4*)(src + 4);
            short8 s;
            s[0] = (short)f2bf(a.x); s[1] = (short)f2bf(a.y);
            s[2] = (short)f2bf(a.z); s[3] = (short)f2bf(a.w);
            s[4] = (short)f2bf(b.x); s[5] = (short)f2bf(b.y);
            s[6] = (short)f2bf(b.z); s[7] = (short)f2bf(b.w);
            wi[mt][kb] = s;
        }
    }
    float4 bias[4];
#pragma unroll
    for (int mt = 0; mt < 4; ++mt) {
        const int j0 = w * 64 + mt * 16 + quad * 4;
        float4 b1 = *(const float4*)(bic + j0);
        float4 b2 = *(const float4*)(bcc + j0);
        bias[mt] = (float4){b1.x + b2.x, b1.y + b2.y, b1.z + b2.z, b1.w + b2.w};
    }
    // init buf0: ctx=0 (granule rows 0..31), x_0 (rows 32..39)
    *(uint4*)(bufs + tid * 16) = (uint4){0, 0, 0, 0};
    *(uint4*)(bufs + (tid + 256) * 16) = (uint4){0, 0, 0, 0};
    {
        float4 xv = *(const float4*)(x + (size_t)(g * 16 + bq) * 64 + o4 * 4);
        short4v s4;
        s4[0] = (short)f2bf(xv.x); s4[1] = (short)f2bf(xv.y);
        s4[2] = (short)f2bf(xv.z); s4[3] = (short)f2bf(xv.w);
        *(short4v*)(bufs + (32 + (o4 >> 1)) * 256 + bq * 16 + (o4 & 1) * 8) = s4;
    }
    float4 y[4];
#pragma unroll
    for (int mt = 0; mt < 4; ++mt) y[mt] = (float4){0.f, 0.f, 0.f, 0.f};
    __syncthreads();

    int p = 0;
#pragma unroll 1
    for (int t = 0; t < 256; ++t) {
        char* bp = bufs + p * 10240;
        char* bn = bufs + (p ^ 1) * 10240;
#pragma unroll
        for (int mt = 0; mt < 4; ++mt) {
            const int j0 = w * 64 + mt * 16 + quad * 4;
#pragma unroll
            for (int r = 0; r < 4; ++r)
                CTXT[(size_t)(j0 + r) * 32768 + t * 128 + g * 16 + l15] = (&y[mt].x)[r];
        }
        float4 xv;
        if (t < 255)
            xv = *(const float4*)(x + (size_t)((t + 1) * 128 + g * 16 + bq) * 64 + o4 * 4);
        floatx4 acc[4];
#pragma unroll
        for (int mt = 0; mt < 4; ++mt) acc[mt] = (floatx4){0.f, 0.f, 0.f, 0.f};
#pragma unroll
        for (int kb = 0; kb < 8; ++kb) {
            short8 bf = *(const short8*)(bp + (kb * 4 + quad) * 256 + l15 * 16);
#pragma unroll
            for (int mt = 0; mt < 4; ++mt)
                acc[mt] = __builtin_amdgcn_mfma_f32_16x16x32_bf16(wf[mt][kb], bf, acc[mt], 0, 0, 0);
        }
#pragma unroll
        for (int kb = 0; kb < 2; ++kb) {
            short8 bf = *(const short8*)(bp + ((8 + kb) * 4 + quad) * 256 + l15 * 16);
#pragma unroll
            for (int mt = 0; mt < 4; ++mt)
                acc[mt] = __builtin_amdgcn_mfma_f32_16x16x32_bf16(wi[mt][kb], bf, acc[mt], 0, 0, 0);
        }
#pragma unroll
        for (int mt = 0; mt < 4; ++mt) {
            y[mt].x = fmaxf(acc[mt][0] + bias[mt].x, 0.f);
            y[mt].y = fmaxf(acc[mt][1] + bias[mt].y, 0.f);
            y[mt].z = fmaxf(acc[mt][2] + bias[mt].z, 0.f);
            y[mt].w = fmaxf(acc[mt][3] + bias[mt].w, 0.f);
        }
        if (t < 255) {
#pragma unroll
            for (int mt = 0; mt < 4; ++mt) {
                const int c0 = w * 64 + mt * 16 + quad * 4;
                short4v s4;
                s4[0] = (short)f2bf(y[mt].x); s4[1] = (short)f2bf(y[mt].y);
                s4[2] = (short)f2bf(y[mt].z); s4[3] = (short)f2bf(y[mt].w);
                *(short4v*)(bn + (c0 >> 3) * 256 + l15 * 16 + (c0 & 7) * 2) = s4;
            }
            short4v s4;
            s4[0] = (short)f2bf(xv.x); s4[1] = (short)f2bf(xv.y);
            s4[2] = (short)f2bf(xv.z); s4[3] = (short)f2bf(xv.w);
            *(short4v*)(bn + (32 + (o4 >> 1)) * 256 + bq * 16 + (o4 & 1) * 8) = s4;
        }
        __syncthreads();
        p ^= 1;
    }
#pragma unroll
    for (int mt = 0; mt < 4; ++mt) {
        const int j0 = w * 64 + mt * 16 + quad * 4;
#pragma unroll
        for (int r = 0; r < 4; ++r)
            ctx_out[(size_t)(g * 16 + l15) * 256 + j0 + r] = (&y[mt].x)[r];
    }
}

// ---------------------------------------------------------------------------
// BIG GEMM: M=32768,N=512,K=16448, per-c scale folded into A-frags (fp32 x
// resident in regs, v_mul+v_perm pack). 512 thr / 8 waves (4m x 2n), wave
// tile 32m x 64n. BK=128, LDS double-buffer (2x32 KB), glds(16B) prefetch.
// 1D grid 1024, XCD swizzle: by = gidx&3 (one WbT slice per XCD).
// ---------------------------------------------------------------------------
__global__ __launch_bounds__(512, 4) void k_big(const float* __restrict__ xf,
                                                const ushort_t* __restrict__ WbT,
                                                const float* __restrict__ CTXT,
                                                ushort_t* __restrict__ hbf) {
    __shared__ __align__(16) ushort_t Bt[2 * 128 * 128];   // 64 KB
    const int tid = threadIdx.x;
    const int lane = tid & 63, w = tid >> 6;               // 8 waves
    const int wm = w & 3, wn = w >> 2;                     // 4m x 2n
    const int l15 = lane & 15, quad = lane >> 4;
    const int gidx = blockIdx.x;
    const int by = gidx & 3;                               // xcd = gidx&7
    const int bx = (gidx >> 3) * 2 + ((gidx >> 2) & 1);
    const int m0 = bx * 128, n0 = by * 128;

    // fp32 x rows, frag order: xr[mt][0..7] = x[row][quad*8+j] (ks=0),
    //                          xr[mt][8..15] = x[row][32+quad*8+j] (ks=1)
    float xr[2][16];
#pragma unroll
    for (int mt = 0; mt < 2; ++mt) {
        const int row = m0 + wm * 32 + mt * 16 + l15;
        const float* xp = xf + (size_t)row * 64 + quad * 8;
        *(float4*)(&xr[mt][0])  = *(const float4*)(xp + 0);
        *(float4*)(&xr[mt][4])  = *(const float4*)(xp + 4);
        *(float4*)(&xr[mt][8])  = *(const float4*)(xp + 32);
        *(float4*)(&xr[mt][12]) = *(const float4*)(xp + 36);
    }

    floatx4 acc[2][4];
#pragma unroll
    for (int i = 0; i < 2; ++i)
#pragma unroll
        for (int j = 0; j < 4; ++j) acc[i][j] = (floatx4){0.f, 0.f, 0.f, 0.f};

    // staging: granule G = w*256 + q*64 + lane; nr=G>>4; k8=(G&15)^(nr&15)
    const ushort_t* gq[4];
    ushort_t* lq[4];
#pragma unroll
    for (int q = 0; q < 4; ++q) {
        const int G = w * 256 + q * 64 + lane;
        const int nr = G >> 4;
        const int k8 = (G & 15) ^ (nr & 15);
        gq[q] = WbT + (size_t)(n0 + nr) * 16448 + k8 * 8;
        lq[q] = Bt + w * 2048 + q * 512;                   // wave-uniform base
    }
#pragma unroll
    for (int q = 0; q < 4; ++q) glds16(gq[q], lq[q]);      // tile 0 -> buf 0

    // sc[h][mt] for kk=0
    float sv[2][2], sn[2][2];
#pragma unroll
    for (int h = 0; h < 2; ++h)
#pragma unroll
        for (int mt = 0; mt < 2; ++mt)
            sv[h][mt] = CTXT[(size_t)h * 32768 + m0 + wm * 32 + mt * 16 + l15];

    for (int kk = 0; kk < 129; ++kk) {
        const int p = kk & 1;
        __syncthreads();                                   // buf p resident
        if (kk < 128) {                                    // prefetch kk+1 -> p^1
            const size_t koff = (size_t)(kk + 1) * 128;
            const int np = (p ^ 1) * 16384;
#pragma unroll
            for (int q = 0; q < 4; ++q) glds16(gq[q] + koff, lq[q] + np);
        }
        if (kk + 1 < 128) {
#pragma unroll
            for (int h = 0; h < 2; ++h)
#pragma unroll
                for (int mt = 0; mt < 2; ++mt)
                    sn[h][mt] = CTXT[(size_t)(2 * kk + 2 + h) * 32768 + m0 + wm * 32 + mt * 16 + l15];
        } else {
#pragma unroll
            for (int h = 0; h < 2; ++h)
#pragma unroll
                for (int mt = 0; mt < 2; ++mt) sn[h][mt] = 1.f;
        }
        const ushort_t* bb = Bt + p * 16384;
        const int hmax = (kk < 128) ? 2 : 1;
        for (int h = 0; h < hmax; ++h) {
            short8 a0 = mkfrag(&xr[0][0], sv[h][0]);       // ks=0
            short8 a1 = mkfrag(&xr[1][0], sv[h][1]);
            short8 c0 = mkfrag(&xr[0][8], sv[h][0]);       // ks=1
            short8 c1 = mkfrag(&xr[1][8], sv[h][1]);
#pragma unroll
            for (int nt = 0; nt < 4; ++nt) {
                const int nr = wn * 64 + nt * 16 + l15;
                const ushort_t* bpr = bb + nr * 128;
                const int g0 = h * 8 + quad, g1 = h * 8 + 4 + quad;
                short8 b0 = *(const short8*)(bpr + (g0 ^ l15) * 8);
                short8 b1 = *(const short8*)(bpr + (g1 ^ l15) * 8);
                acc[0][nt] = __builtin_amdgcn_mfma_f32_16x16x32_bf16(a0, b0, acc[0][nt], 0, 0, 0);
                acc[1][nt] = __builtin_amdgcn_mfma_f32_16x16x32_bf16(a1, b0, acc[1][nt], 0, 0, 0);
                acc[0][nt] = __builtin_amdgcn_mfma_f32_16x16x32_bf16(c0, b1, acc[0][nt], 0, 0, 0);
                acc[1][nt] = __builtin_amdgcn_mfma_f32_16x16x32_bf16(c1, b1, acc[1][nt], 0, 0, 0);
            }
        }
#pragma unroll
        for (int h = 0; h < 2; ++h)
#pragma unroll
            for (int mt = 0; mt < 2; ++mt) sv[h][mt] = sn[h][mt];
    }
    // epilogue: col = n0+wn*64+nt*16+l15, row = m0+wm*32+mt*16+quad*4+r
#pragma unroll
    for (int mt = 0; mt < 2; ++mt)
#pragma unroll
        for (int nt = 0; nt < 4; ++nt) {
            const int col = n0 + wn * 64 + nt * 16 + l15;
#pragma unroll
            for (int r = 0; r < 4; ++r) {
                const int row = m0 + wm * 32 + mt * 16 + quad * 4 + r;
                hbf[(size_t)row * 512 + col] = f2bf(fmaxf(acc[mt][nt][r], 0.f));
            }
        }
}

// ---------------------------------------------------------------------------
// Generic bf16 NT GEMM: C[m,n] = sum_k A[m,k]*B[n,k] + bias[n]
// ---------------------------------------------------------------------------
template <bool OUTF32>
__global__ __launch_bounds__(256, 2) void k_gemm_nt(const ushort_t* __restrict__ A,
                                                    const ushort_t* __restrict__ Bm,
                                                    const float* __restrict__ bias,
                                                    ushort_t* __restrict__ outb,
                                                    float* __restrict__ outf,
                                                    int K, int Nst) {
    __shared__ __align__(16) ushort_t At[128 * 72];
    __shared__ __align__(16) ushort_t Bt[128 * 72];
    const int tid = threadIdx.x;
    const int lane = tid & 63, w = tid >> 6;
    const int wm = w & 1, wn = w >> 1;
    const int l15 = lane & 15, quad = lane >> 4;
    const int m0 = blockIdx.x * 128, n0 = blockIdx.y * 128;

    const int r_l = tid >> 1, kh = (tid & 1) * 32;
    const ushort_t* gA = A + (size_t)(m0 + r_l) * K + kh;
    const ushort_t* gB = Bm + (size_t)(n0 + r_l) * K + kh;
    ushort_t* lA = &At[r_l * 72 + kh];
    ushort_t* lB = &Bt[r_l * 72 + kh];

    uint4 ra0 = *(const uint4*)(gA + 0), ra1 = *(const uint4*)(gA + 8);
    uint4 ra2 = *(const uint4*)(gA + 16), ra3 = *(const uint4*)(gA + 24);
    uint4 rb0 = *(const uint4*)(gB + 0), rb1 = *(const uint4*)(gB + 8);
    uint4 rb2 = *(const uint4*)(gB + 16), rb3 = *(const uint4*)(gB + 24);

    floatx4 acc[4][4];
#pragma unroll
    for (int i = 0; i < 4; ++i)
#pragma unroll
        for (int j = 0; j < 4; ++j) acc[i][j] = (floatx4){0.f, 0.f, 0.f, 0.f};

    const int niter = K >> 6;
    for (int kb = 0; kb < niter; ++kb) {
        __syncthreads();
        *(uint4*)(lA + 0) = ra0;  *(uint4*)(lA + 8) = ra1;
        *(uint4*)(lA + 16) = ra2; *(uint4*)(lA + 24) = ra3;
        *(uint4*)(lB + 0) = rb0;  *(uint4*)(lB + 8) = rb1;
        *(uint4*)(lB + 16) = rb2; *(uint4*)(lB + 24) = rb3;
        __syncthreads();
        if (kb + 1 < niter) {
            const ushort_t* ga = gA + (size_t)(kb + 1) * 64;
            const ushort_t* gb = gB + (size_t)(kb + 1) * 64;
            ra0 = *(const uint4*)(ga + 0);  ra1 = *(const uint4*)(ga + 8);
            ra2 = *(const uint4*)(ga + 16); ra3 = *(const uint4*)(ga + 24);
            rb0 = *(const uint4*)(gb + 0);  rb1 = *(const uint4*)(gb + 8);
            rb2 = *(const uint4*)(gb + 16); rb3 = *(const uint4*)(gb + 24);
        }
        short8 av[4][2];
#pragma unroll
        for (int mt = 0; mt < 4; ++mt) {
            const int mr = wm * 64 + mt * 16 + l15;
            av[mt][0] = *(const short8*)(&At[mr * 72 + quad * 8]);
            av[mt][1] = *(const short8*)(&At[mr * 72 + 32 + quad * 8]);
        }
#pragma unroll
        for (int nt = 0; nt < 4; ++nt) {
            const int nr = wn * 64 + nt * 16 + l15;
            short8 b0 = *(const short8*)(&Bt[nr * 72 + quad * 8]);
            short8 b1 = *(const short8*)(&Bt[nr * 72 + 32 + quad * 8]);
#pragma unroll
            for (int mt = 0; mt < 4; ++mt) {
                acc[mt][nt] = __builtin_amdgcn_mfma_f32_16x16x32_bf16(av[mt][0], b0, acc[mt][nt], 0, 0, 0);
                acc[mt][nt] = __builtin_amdgcn_mfma_f32_16x16x32_bf16(av[mt][1], b1, acc[mt][nt], 0, 0, 0);
            }
        }
    }
#pragma unroll
    for (int mt = 0; mt < 4; ++mt)
#pragma unroll
        for (int nt = 0; nt < 4; ++nt) {
            const int col = n0 + wn * 64 + nt * 16 + l15;
            const float bb = bias[col];
#pragma unroll
            for (int r = 0; r < 4; ++r) {
                const int row = m0 + wm * 64 + mt * 16 + quad * 4 + r;
                const float v = acc[mt][nt][r] + bb;
                if (OUTF32) outf[(size_t)row * Nst + col] = v;
                else        outb[(size_t)row * Nst + col] = f2bf(v);
            }
        }
}

// ---------------------------------------------------------------------------
// LayerNorm + residual: z = h + relu( LN(hn)*g + b ), in-place over hbf.
// ---------------------------------------------------------------------------
__global__ __launch_bounds__(256, 1) void k_ln(const ushort_t* __restrict__ hn,
                                               ushort_t* __restrict__ h,
                                               const float* __restrict__ g,
                                               const float* __restrict__ bb) {
    const int tid = threadIdx.x;
    const int lane = tid & 63;
    const int row = blockIdx.x * 4 + (tid >> 6);
    const uint4 hv = *(const uint4*)(hn + (size_t)row * 512 + lane * 8);
    float f[8];
    f[0] = blo(hv.x); f[1] = bhi(hv.x); f[2] = blo(hv.y); f[3] = bhi(hv.y);
    f[4] = blo(hv.z); f[5] = bhi(hv.z); f[6] = blo(hv.w); f[7] = bhi(hv.w);
    float s = 0.f, s2 = 0.f;
#pragma unroll
    for (int j = 0; j < 8; ++j) { s += f[j]; s2 = fmaf(f[j], f[j], s2); }
#pragma unroll
    for (int o = 32; o >= 1; o >>= 1) { s += __shfl_xor(s, o, 64); s2 += __shfl_xor(s2, o, 64); }
    const float mu = s * (1.f / 512.f);
    const float var = s2 * (1.f / 512.f) - mu * mu;
    const float rs = rsqrtf(var + 1e-5f);
    const uint4 hh = *(const uint4*)(h + (size_t)row * 512 + lane * 8);
    float hf[8];
    hf[0] = blo(hh.x); hf[1] = bhi(hh.x); hf[2] = blo(hh.y); hf[3] = bhi(hh.y);
    hf[4] = blo(hh.z); hf[5] = bhi(hh.z); hf[6] = blo(hh.w); hf[7] = bhi(hh.w);
    float4 g0 = *(const float4*)(g + lane * 8);  float4 g1 = *(const float4*)(g + lane * 8 + 4);
    float4 b0 = *(const float4*)(bb + lane * 8); float4 b1 = *(const float4*)(bb + lane * 8 + 4);
    const float gv[8] = {g0.x, g0.y, g0.z, g0.w, g1.x, g1.y, g1.z, g1.w};
    const float bv[8] = {b0.x, b0.y, b0.z, b0.w, b1.x, b1.y, b1.z, b1.w};
    float z[8];
#pragma unroll
    for (int j = 0; j < 8; ++j)
        z[j] = hf[j] + fmaxf((f[j] - mu) * rs * gv[j] + bv[j], 0.f);
    uint4 o;
    o.x = pack2(z[0], z[1]); o.y = pack2(z[2], z[3]);
    o.z = pack2(z[4], z[5]); o.w = pack2(z[6], z[7]);
    *(uint4*)(h + (size_t)row * 512 + lane * 8) = o;
}

// ---------------------------------------------------------------------------
extern "C" void kernel_launch(void* const* d_in, const int* in_sizes, int n_in,
                              void* d_out, int out_size, void* d_ws, size_t ws_size,
                              hipStream_t stream) {
    const float* x    = (const float*)d_in[0];
    const float* Wcc  = (const float*)d_in[1];
    const float* bcc  = (const float*)d_in[2];
    const float* Wic  = (const float*)d_in[3];
    const float* bic  = (const float*)d_in[4];
    const float* Wmap = (const float*)d_in[5];
    const float* bmap = (const float*)d_in[6];
    const float* Whh  = (const float*)d_in[7];
    const float* bhh  = (const float*)d_in[8];
    const float* ln_g = (const float*)d_in[9];
    const float* ln_b = (const float*)d_in[10];
    const float* Who  = (const float*)d_in[11];
    const float* bho  = (const float*)d_in[12];
    float* out = (float*)d_out;

    char* wsb = (char*)d_ws;
    ushort_t* WbT  = (ushort_t*)(wsb);                    // 16,842,752 B + 1 KB pad
    ushort_t* Whhb = (ushort_t*)(wsb + 16843776);         //    524,288
    ushort_t* Whob = (ushort_t*)(wsb + 17368064);         //    131,072
    float*    CTXT = (float*)   (wsb + 21693440);         // 33,554,432
    ushort_t* hbf  = (ushort_t*)(wsb + 55247872);         // 33,554,432 (h, then z)
    ushort_t* hnbf = (ushort_t*)(wsb + 88802304);         // 33,554,432 -> ~122 MB

    k_fused<<<540, 256, 0, stream>>>(x, Wcc, bcc, Wic, bic, Wmap, bmap, Whh, Who,
                                     WbT, Whhb, Whob, CTXT, out + 4194304);
    k_big<<<1024, 512, 0, stream>>>(x, WbT, CTXT, hbf);
    k_gemm_nt<false><<<dim3(256, 4), 256, 0, stream>>>(hbf, Whhb, bhh, hnbf, nullptr, 512, 512);
    k_ln<<<8192, 256, 0, stream>>>(hnbf, hbf, ln_g, ln_b);
    k_gemm_nt<true><<<dim3(256, 1), 256, 0, stream>>>(hbf, Whob, bho, nullptr, out, 512, 128);
}